// Round 4
// baseline (628.100 us; speedup 1.0000x reference)
//
#include <hip/hip_runtime.h>

#define N_ENTITIES 200000
#define N_ITEMS    100000
#define DIM        64
#define N_EDGES    1500000
#define K_EDGES    256
#define K_ITEMS    100
// 1 / (2 * sqrt(32))  (mean over 2 heads of per-head 1/sqrt(Dk))
#define SCALE      0.08838834764831845f

#define CAND_CAP   4096
#define NXCD       8

// ---- monotonic float<->u32 key (order-preserving, total order) ----
__device__ __forceinline__ unsigned fkey(float x) {
    unsigned u = __float_as_uint(x);
    return (u & 0x80000000u) ? ~u : (u | 0x80000000u);
}
__device__ __forceinline__ float funkey(unsigned k) {
    return (k & 0x80000000u) ? __uint_as_float(k & 0x7fffffffu)
                             : __uint_as_float(~k);
}

template<bool LOCAL>
__device__ __forceinline__ void atadd(float* p, float v) {
    if (LOCAL)
        (void)__hip_atomic_fetch_add(p, v, __ATOMIC_RELAXED, __HIP_MEMORY_SCOPE_WORKGROUP);
    else
        atomicAdd(p, v);
}

// wave-aggregated LDS histogram add: one LDS atomic per distinct bin per wave
__device__ __forceinline__ void lds_hist_add(unsigned* h, unsigned bin, bool valid, int lane) {
    bool need = valid;
    for (;;) {
        unsigned long long mask = __ballot(need);
        if (mask == 0ull) break;
        int leader = __ffsll(mask) - 1;
        unsigned lbin = __shfl(bin, leader, 64);
        bool same = need && (bin == lbin);
        unsigned long long grp = __ballot(same);
        if (lane == leader) atomicAdd(&h[lbin], (unsigned)__popcll(grp));
        need = need && !same;
    }
}

// serial 256-bin select (uniform, scalar-cached): largest bin b with
// count(> b) < Keff <= count(>= b). Returns bin; *above = count strictly above.
__device__ __forceinline__ unsigned select_digit(const unsigned* __restrict__ hist,
                                                 unsigned Keff, unsigned* above) {
    unsigned cum = 0;
    int b = 255;
    for (; b > 0; --b) {
        unsigned hb = hist[b];
        if (cum + hb >= Keff) break;
        cum += hb;
    }
    *above = cum;
    return (unsigned)b;
}

// ---- proj = emb @ W_Q ----
// Block = 256 threads = (q in [0,4)) x (c in [0,64)). Each block does 16 rows.
// Thread holds W[q*16+j][c]; emb values wave-uniform -> scalar loads via K$.
__global__ __launch_bounds__(256) void proj_kernel(const float* __restrict__ emb,
                                                   const float* __restrict__ W,
                                                   float* __restrict__ proj) {
    __shared__ float part[4][16][64];
    const int t = threadIdx.x;
    const int c = t & 63;
    const int q = __builtin_amdgcn_readfirstlane(t >> 6);

    float Wreg[16];
#pragma unroll
    for (int j = 0; j < 16; ++j) Wreg[j] = W[(q * 16 + j) * 64 + c];

    const int base = blockIdx.x * 16;   // 200000 = 12500 * 16, exact
    const float* erow = emb + (size_t)base * 64 + q * 16;

    float acc[16];
#pragma unroll
    for (int r = 0; r < 16; ++r) acc[r] = 0.f;
#pragma unroll
    for (int r = 0; r < 16; ++r) {
#pragma unroll
        for (int j = 0; j < 16; ++j)
            acc[r] += erow[r * 64 + j] * Wreg[j];
    }
#pragma unroll
    for (int r = 0; r < 16; ++r) part[q][r][c] = acc[r];
    __syncthreads();
#pragma unroll
    for (int it = 0; it < 4; ++it) {
        int oi = t + it * 256;
        int r = oi >> 6, cc = oi & 63;
        float s = part[0][r][cc] + part[1][r][cc] + part[2][r][cc] + part[3][r][cc];
        proj[(size_t)(base + r) * 64 + cc] = s;
    }
}

// ---- fused edge pass: logits + denom(exp) + deg + sum_by_node ----
// 8 edges per wave (2 per 16-lane slot). LOCAL=true: per-XCD replica +
// L2-resident (workgroup-scope) atomics; partition keyed by physical XCC_ID
// so every block updating replica r shares replica r's L2 (correct by
// construction; end-of-kernel release flush publishes to the reduce pass).
template<bool LOCAL>
__global__ __launch_bounds__(256) void edge_fused(const float4* __restrict__ proj4,
                                                  const float4* __restrict__ rel4,
                                                  const int* __restrict__ head,
                                                  const int* __restrict__ tail,
                                                  const int* __restrict__ etype,
                                                  float* __restrict__ logits,
                                                  float* __restrict__ ndR,   // [R][2*N_ENTITIES]
                                                  float* __restrict__ sumR)  // [R][N_ENTITIES]
{
    unsigned rep = 0;
    if (LOCAL) {
        unsigned x;
        asm volatile("s_getreg_b32 %0, hwreg(HW_REG_XCC_ID)" : "=s"(x));
        rep = x & (NXCD - 1);
    }
    float* nd = ndR + (size_t)rep * (2 * N_ENTITIES);
    float* sn = sumR + (size_t)rep * N_ENTITIES;

    int wave = (blockIdx.x * blockDim.x + threadIdx.x) >> 6;
    int lane = threadIdx.x & 63;
    int slot = lane >> 4, sl = lane & 15;
    int base = wave * 8;                 // N_EDGES % 8 == 0, grid sized exactly
    int e0 = base + slot, e1 = base + slot + 4;

    int h0 = head[e0], t0 = tail[e0], r0 = etype[e0] - 1;
    int h1 = head[e1], t1 = tail[e1], r1 = etype[e1] - 1;
    float4 a0 = proj4[(size_t)h0 * 16 + sl];
    float4 b0 = proj4[(size_t)t0 * 16 + sl];
    float4 a1 = proj4[(size_t)h1 * 16 + sl];
    float4 b1 = proj4[(size_t)t1 * 16 + sl];
    float4 c0 = rel4[(size_t)r0 * 16 + sl];
    float4 c1 = rel4[(size_t)r1 * 16 + sl];

    float s0 = a0.x * b0.x * c0.x + a0.y * b0.y * c0.y + a0.z * b0.z * c0.z + a0.w * b0.w * c0.w;
    float s1 = a1.x * b1.x * c1.x + a1.y * b1.y * c1.y + a1.z * b1.z * c1.z + a1.w * b1.w * c1.w;
    s0 += __shfl_xor(s0, 1, 64);  s1 += __shfl_xor(s1, 1, 64);
    s0 += __shfl_xor(s0, 2, 64);  s1 += __shfl_xor(s1, 2, 64);
    s0 += __shfl_xor(s0, 4, 64);  s1 += __shfl_xor(s1, 4, 64);
    s0 += __shfl_xor(s0, 8, 64);  s1 += __shfl_xor(s1, 8, 64);

    if (sl == 0) {
        float lg0 = s0 * SCALE, lg1 = s1 * SCALE;
        logits[e0] = lg0;
        logits[e1] = lg1;
        atadd<LOCAL>(&nd[2 * h0], __expf(lg0));
        atadd<LOCAL>(&nd[2 * h0 + 1], 1.0f);
        atadd<LOCAL>(&sn[h0], lg0);
        atadd<LOCAL>(&sn[t0], lg0);
        atadd<LOCAL>(&nd[2 * h1], __expf(lg1));
        atadd<LOCAL>(&nd[2 * h1 + 1], 1.0f);
        atadd<LOCAL>(&sn[h1], lg1);
        atadd<LOCAL>(&sn[t1], lg1);
    }
}

// ---- fold replicas; emit item keys + item stage-0 histogram ----
// nd final = replica 0 accumulated in place.
template<int NREP>
__global__ void reduce_kernel(float* __restrict__ ndR, const float* __restrict__ sumR,
                              unsigned* __restrict__ keysI, unsigned* __restrict__ histA_I) {
    __shared__ unsigned h[256];
    for (int j = threadIdx.x; j < 256; j += blockDim.x) h[j] = 0;
    __syncthreads();
    int i = blockIdx.x * blockDim.x + threadIdx.x;
    int lane = threadIdx.x & 63;
    unsigned bin = 0;
    bool valid = false;
    if (i < N_ENTITIES) {
        float2* nd2 = (float2*)ndR;
        if (NREP > 1) {
            float2 acc = nd2[i];
#pragma unroll
            for (int r = 1; r < NREP; ++r) {
                float2 v = nd2[(size_t)r * N_ENTITIES + i];
                acc.x += v.x;
                acc.y += v.y;
            }
            nd2[i] = acc;
        }
        if (i < N_ITEMS) {
            float s = sumR[i];
#pragma unroll
            for (int r = 1; r < NREP; ++r) s += sumR[(size_t)r * N_ENTITIES + i];
            unsigned k = fkey(s);
            keysI[i] = k;
            bin = k >> 24;
            valid = true;
        }
    }
    lds_hist_add(h, bin, valid, lane);
    __syncthreads();
    for (int j = threadIdx.x; j < 256; j += blockDim.x) {
        unsigned v = h[j];
        if (v) atomicAdd(&histA_I[j], v);
    }
}

// ---- scores + gumbel keys + edge stage-0 histogram ----
__global__ void edge_pass3(const float* __restrict__ logits, const int* __restrict__ head,
                           const float2* __restrict__ nd, const float* __restrict__ noise_u,
                           float* __restrict__ out_scores, unsigned* __restrict__ keysE,
                           unsigned* __restrict__ histA_E) {
    __shared__ unsigned h[256];
    for (int j = threadIdx.x; j < 256; j += blockDim.x) h[j] = 0;
    __syncthreads();
    int i = blockIdx.x * blockDim.x + threadIdx.x;
    int lane = threadIdx.x & 63;
    unsigned bin = 0;
    bool valid = (i < N_EDGES);
    if (valid) {
        float lg = logits[i];
        float2 dd = nd[head[i]];
        float score = __expf(lg) / dd.x * dd.y;
        out_scores[i] = score;
        float noise = -logf(-logf(noise_u[i]));   // library logf: accurate near u->1
        unsigned k = fkey(score + noise);
        keysE[i] = k;
        bin = k >> 24;
    }
    lds_hist_add(h, bin, valid, lane);
    __syncthreads();
    for (int j = threadIdx.x; j < 256; j += blockDim.x) {
        unsigned v = h[j];
        if (v) atomicAdd(&histA_E[j], v);
    }
}

// ---- radix stages 1,2: recompute selects inline, histogram next digit ----
// grid.y: 0 = edges, 1 = items. hists layout: [y][stage][256].
__global__ void hist_stage_kernel(const unsigned* __restrict__ keysE,
                                  const unsigned* __restrict__ keysI,
                                  unsigned* __restrict__ hists, int stage) {
    __shared__ unsigned h[256];
    for (int j = threadIdx.x; j < 256; j += blockDim.x) h[j] = 0;
    __syncthreads();
    const int y = blockIdx.y;
    const unsigned* keys = y ? keysI : keysE;
    const int n = y ? N_ITEMS : N_EDGES;
    const unsigned K = y ? K_ITEMS : K_EDGES;
    unsigned* H = hists + (size_t)y * 3 * 256;

    unsigned aboveA, prefix;
    unsigned binA = select_digit(H, K, &aboveA);
    if (stage == 1) {
        prefix = binA;
    } else {
        unsigned aboveB;
        unsigned binB = select_digit(H + 256, K - aboveA, &aboveB);
        prefix = (binA << 8) | binB;
    }
    const int shift = 24 - 8 * stage;   // 16 or 8
    unsigned* out = H + stage * 256;

    const int lane = threadIdx.x & 63;
    const int stride = gridDim.x * blockDim.x;
    for (int idx = blockIdx.x * blockDim.x + threadIdx.x; idx - lane < n; idx += stride) {
        bool valid = (idx < n);
        unsigned bin = 0;
        if (valid) {
            unsigned k = keys[idx];
            if ((k >> (shift + 8)) != prefix) valid = false;
            bin = (k >> shift) & 0xFFu;
        }
        lds_hist_add(h, bin, valid, lane);
    }
    __syncthreads();
    for (int j = threadIdx.x; j < 256; j += blockDim.x) {
        unsigned v = h[j];
        if (v) atomicAdd(&out[j], v);
    }
}

// ---- collect candidates >= 24-bit threshold (both pipelines) ----
__global__ void collect_kernel(const unsigned* __restrict__ keysE,
                               const unsigned* __restrict__ keysI,
                               const unsigned* __restrict__ hists,
                               unsigned* __restrict__ counters, unsigned* __restrict__ cand) {
    const int y = blockIdx.y;
    const unsigned* keys = y ? keysI : keysE;
    const int n = y ? N_ITEMS : N_EDGES;
    const unsigned K = y ? K_ITEMS : K_EDGES;
    const unsigned* H = hists + (size_t)y * 3 * 256;
    unsigned aboveA, aboveB, aboveC;
    unsigned binA = select_digit(H, K, &aboveA);
    unsigned binB = select_digit(H + 256, K - aboveA, &aboveB);
    unsigned binC = select_digit(H + 512, K - aboveA - aboveB, &aboveC);
    const unsigned T = ((binA << 16) | (binB << 8) | binC) << 8;
    unsigned* cd = cand + (size_t)y * 2 * CAND_CAP;

    int i = blockIdx.x * blockDim.x + threadIdx.x;
    int stride = gridDim.x * blockDim.x;
    for (; i < n; i += stride) {
        unsigned k = keys[i];
        if (k >= T) {
            unsigned p = atomicAdd(&counters[y], 1u);
            if (p < (unsigned)CAND_CAP) { cd[2 * p] = k; cd[2 * p + 1] = (unsigned)i; }
        }
    }
}

// ---- exact rank among candidates (key desc, index asc); 2 blocks (y) ----
__global__ void final_topk_kernel(const unsigned* __restrict__ cand,
                                  const unsigned* __restrict__ counters,
                                  float* __restrict__ out_topkv, float* __restrict__ out_topki,
                                  float* __restrict__ out_itemv, float* __restrict__ out_itemi) {
    __shared__ unsigned sk[CAND_CAP];
    __shared__ unsigned si[CAND_CAP];
    const int y = blockIdx.x;
    const int K = y ? K_ITEMS : K_EDGES;
    float* outv = y ? out_itemv : out_topkv;
    float* outi = y ? out_itemi : out_topki;
    const unsigned* cd = cand + (size_t)y * 2 * CAND_CAP;
    unsigned m = counters[y];
    if (m > (unsigned)CAND_CAP) m = CAND_CAP;
    for (unsigned i = threadIdx.x; i < m; i += blockDim.x) {
        sk[i] = cd[2 * i];
        si[i] = cd[2 * i + 1];
    }
    __syncthreads();
    for (unsigned i = threadIdx.x; i < m; i += blockDim.x) {
        unsigned ki = sk[i], xi = si[i];
        int r = 0;
        for (unsigned j = 0; j < m; ++j) {
            unsigned kj = sk[j];
            if (kj > ki || (kj == ki && si[j] < xi)) r++;
        }
        if (r < K) {
            outv[r] = funkey(ki);
            outi[r] = (float)xi;
        }
    }
}

extern "C" void kernel_launch(void* const* d_in, const int* in_sizes, int n_in,
                              void* d_out, int out_size, void* d_ws, size_t ws_size,
                              hipStream_t stream) {
    (void)in_sizes; (void)n_in; (void)out_size;
    const float* emb    = (const float*)d_in[0];
    const float* W      = (const float*)d_in[1];
    const float* rel    = (const float*)d_in[2];
    const float* noise  = (const float*)d_in[3];
    const int*   eidx   = (const int*)d_in[4];
    const int*   etype  = (const int*)d_in[5];
    const int* head = eidx;
    const int* tail = eidx + N_EDGES;

    float* out        = (float*)d_out;
    float* out_scores = out;                                   // [E]
    float* out_topkv  = out + N_EDGES;                         // [256]
    float* out_topki  = out + N_EDGES + K_EDGES;               // [256] (as float)
    float* out_itemv  = out + N_EDGES + 2 * K_EDGES;           // [100]
    float* out_itemi  = out + N_EDGES + 2 * K_EDGES + K_ITEMS; // [100] (as float)

    // layout sized for the replicated path; fall back to R=1 if ws too small
    auto layout_bytes = [](int R) -> size_t {
        size_t f = (size_t)N_ENTITIES * DIM      // proj
                 + N_EDGES                        // logits
                 + N_EDGES                        // keysE
                 + (size_t)R * 2 * N_ENTITIES     // ndR
                 + (size_t)R * N_ENTITIES         // sumR
                 + N_ITEMS                        // keysI
                 + 2 * 3 * 256                    // hists
                 + 2                              // counters
                 + 2 * 2 * CAND_CAP;              // cand
        return f * 4;
    };
    const bool big = ws_size >= layout_bytes(NXCD);
    const int R = big ? NXCD : 1;

    float* ws = (float*)d_ws;
    size_t o = 0;
    float*    proj    = ws + o;              o += (size_t)N_ENTITIES * DIM;
    float*    logits  = ws + o;              o += N_EDGES;
    unsigned* keysE   = (unsigned*)(ws + o); o += N_EDGES;
    float*    ndR     = ws + o;              o += (size_t)R * 2 * N_ENTITIES;
    float*    sumR    = ws + o;              o += (size_t)R * N_ENTITIES;  // contiguous with ndR
    unsigned* keysI   = (unsigned*)(ws + o); o += N_ITEMS;
    unsigned* hists   = (unsigned*)(ws + o); o += 2 * 3 * 256;             // [y][stage][256]
    unsigned* counters= (unsigned*)(ws + o); o += 2;                       // contiguous with hists
    unsigned* cand    = (unsigned*)(ws + o); o += 2 * 2 * CAND_CAP;

    // 1. zero accumulators + histograms/counters
    hipMemsetAsync(ndR, 0, (size_t)R * 3 * N_ENTITIES * 4, stream);
    hipMemsetAsync(hists, 0, (size_t)(2 * 3 * 256 + 2) * 4, stream);
    // 2. projection
    hipLaunchKernelGGL(proj_kernel, dim3(12500), dim3(256), 0, stream, emb, W, proj);
    // 3. fused edge pass (8 edges/wave; 1.5M/8/4 = 46875 blocks exact)
    if (big)
        hipLaunchKernelGGL((edge_fused<true>), dim3(N_EDGES / 8 / 4), dim3(256), 0, stream,
                           (const float4*)proj, (const float4*)rel, head, tail, etype,
                           logits, ndR, sumR);
    else
        hipLaunchKernelGGL((edge_fused<false>), dim3(N_EDGES / 8 / 4), dim3(256), 0, stream,
                           (const float4*)proj, (const float4*)rel, head, tail, etype,
                           logits, ndR, sumR);
    // 4. fold replicas + item keys + item stage-0 hist
    if (big)
        hipLaunchKernelGGL((reduce_kernel<NXCD>), dim3((N_ENTITIES + 255) / 256), dim3(256),
                           0, stream, ndR, sumR, keysI, hists + 3 * 256);
    else
        hipLaunchKernelGGL((reduce_kernel<1>), dim3((N_ENTITIES + 255) / 256), dim3(256),
                           0, stream, ndR, sumR, keysI, hists + 3 * 256);
    // 5. scores + noisy keys + edge stage-0 hist
    hipLaunchKernelGGL(edge_pass3, dim3((N_EDGES + 255) / 256), dim3(256), 0, stream,
                       logits, head, (const float2*)ndR, noise, out_scores, keysE, hists);
    // 6-9. shared top-k pipeline (y=0 edges, y=1 items)
    hipLaunchKernelGGL(hist_stage_kernel, dim3(512, 2), dim3(256), 0, stream,
                       keysE, keysI, hists, 1);
    hipLaunchKernelGGL(hist_stage_kernel, dim3(512, 2), dim3(256), 0, stream,
                       keysE, keysI, hists, 2);
    hipLaunchKernelGGL(collect_kernel, dim3(512, 2), dim3(256), 0, stream,
                       keysE, keysI, hists, counters, cand);
    hipLaunchKernelGGL(final_topk_kernel, dim3(2), dim3(1024), 0, stream,
                       cand, counters, out_topkv, out_topki, out_itemv, out_itemi);
}

// Round 5
// 592.719 us; speedup vs baseline: 1.0597x; 1.0597x over previous
//
#include <hip/hip_runtime.h>

#define N_ENTITIES 200000
#define N_ITEMS    100000
#define DIM        64
#define N_EDGES    1500000
#define K_EDGES    256
#define K_ITEMS    100
// 1 / (2 * sqrt(32))  (mean over 2 heads of per-head 1/sqrt(Dk))
#define SCALE      0.08838834764831845f

#define CAND_CAP   4096
#define NSCANB     ((N_ENTITIES + 255) / 256)   // 782

typedef unsigned long long u64;

// ---- monotonic float<->u32 key (order-preserving, total order) ----
__device__ __forceinline__ unsigned fkey(float x) {
    unsigned u = __float_as_uint(x);
    return (u & 0x80000000u) ? ~u : (u | 0x80000000u);
}
__device__ __forceinline__ float funkey(unsigned k) {
    return (k & 0x80000000u) ? __uint_as_float(k & 0x7fffffffu)
                             : __uint_as_float(~k);
}

// wave-aggregated LDS histogram add: one LDS atomic per distinct bin per wave
__device__ __forceinline__ void lds_hist_add(unsigned* h, unsigned bin, bool valid, int lane) {
    bool need = valid;
    for (;;) {
        unsigned long long mask = __ballot(need);
        if (mask == 0ull) break;
        int leader = __ffsll(mask) - 1;
        unsigned lbin = __shfl(bin, leader, 64);
        bool same = need && (bin == lbin);
        unsigned long long grp = __ballot(same);
        if (lane == leader) atomicAdd(&h[lbin], (unsigned)__popcll(grp));
        need = need && !same;
    }
}

// serial 256-bin select: largest bin b with count(>b) < Keff <= count(>=b).
__device__ __forceinline__ unsigned select_digit(const unsigned* __restrict__ hist,
                                                 unsigned Keff, unsigned* above) {
    unsigned cum = 0;
    int b = 255;
    for (; b > 0; --b) {
        unsigned hb = hist[b];
        if (cum + hb >= Keff) break;
        cum += hb;
    }
    *above = cum;
    return (unsigned)b;
}

// ---- proj = emb @ W_Q, with head-degree histogram fused (atomics hide
// behind the GEMM). Block = 256 thr = (q in [0,4)) x (c in [0,64)); 16 rows/blk.
__global__ __launch_bounds__(256) void proj_kernel(const float* __restrict__ emb,
                                                   const float* __restrict__ W,
                                                   float* __restrict__ proj,
                                                   const int* __restrict__ head,
                                                   unsigned* __restrict__ degi) {
    // fused: degree histogram (grid 12500*256 = 3.2M threads >= N_EDGES)
    if (head) {
        int e = blockIdx.x * blockDim.x + threadIdx.x;
        if (e < N_EDGES) atomicAdd(&degi[head[e]], 1u);
    }
    __shared__ float part[4][16][64];
    const int t = threadIdx.x;
    const int c = t & 63;
    const int q = __builtin_amdgcn_readfirstlane(t >> 6);

    float Wreg[16];
#pragma unroll
    for (int j = 0; j < 16; ++j) Wreg[j] = W[(q * 16 + j) * 64 + c];

    const int base = blockIdx.x * 16;   // 200000 = 12500 * 16, exact
    const float* erow = emb + (size_t)base * 64 + q * 16;

    float acc[16];
#pragma unroll
    for (int r = 0; r < 16; ++r) acc[r] = 0.f;
#pragma unroll
    for (int r = 0; r < 16; ++r) {
#pragma unroll
        for (int j = 0; j < 16; ++j)
            acc[r] += erow[r * 64 + j] * Wreg[j];
    }
#pragma unroll
    for (int r = 0; r < 16; ++r) part[q][r][c] = acc[r];
    __syncthreads();
#pragma unroll
    for (int it = 0; it < 4; ++it) {
        int oi = t + it * 256;
        int r = oi >> 6, cc = oi & 63;
        float s = part[0][r][cc] + part[1][r][cc] + part[2][r][cc] + part[3][r][cc];
        proj[(size_t)(base + r) * 64 + cc] = s;
    }
}

// ---- exclusive scan of degi -> start (3 small kernels) ----
__global__ void scan1_kernel(const unsigned* __restrict__ degi, unsigned* __restrict__ start,
                             unsigned* __restrict__ bsum) {
    __shared__ unsigned s[256];
    int t = threadIdx.x, i = blockIdx.x * 256 + t;
    unsigned v = (i < N_ENTITIES) ? degi[i] : 0u;
    s[t] = v;
    __syncthreads();
    for (int off = 1; off < 256; off <<= 1) {
        unsigned x = s[t];
        unsigned y = (t >= off) ? s[t - off] : 0u;
        __syncthreads();
        s[t] = x + y;
        __syncthreads();
    }
    if (i < N_ENTITIES) start[i] = s[t] - v;   // block-local exclusive
    if (t == 255) bsum[blockIdx.x] = s[t];
}

__global__ void scan2_kernel(const unsigned* __restrict__ bsum, unsigned* __restrict__ bscan) {
    __shared__ unsigned s[1024];
    int t = threadIdx.x;
    unsigned v = (t < NSCANB) ? bsum[t] : 0u;
    s[t] = v;
    __syncthreads();
    for (int off = 1; off < 1024; off <<= 1) {
        unsigned x = s[t];
        unsigned y = (t >= off) ? s[t - off] : 0u;
        __syncthreads();
        s[t] = x + y;
        __syncthreads();
    }
    if (t < NSCANB) bscan[t] = s[t] - v;        // exclusive
}

__global__ void scan3_kernel(unsigned* __restrict__ start, const unsigned* __restrict__ bscan,
                             unsigned* __restrict__ pos) {
    int i = blockIdx.x * 256 + threadIdx.x;
    if (i < N_ENTITIES) {
        unsigned v = start[i] + bscan[i >> 8];
        start[i] = v;
        pos[i] = v;
    }
}

// ---- scatter edges into CSR slots: rec = tail(18b)<<27 | rel(6b)<<21 | eid(21b) ----
__global__ void scatter_kernel(const int* __restrict__ head, const int* __restrict__ tail,
                               const int* __restrict__ etype,
                               unsigned* __restrict__ pos, u64* __restrict__ rec) {
    int i = blockIdx.x * blockDim.x + threadIdx.x;
    if (i >= N_EDGES) return;
    int h = head[i];
    unsigned slot = atomicAdd(&pos[h], 1u);
    u64 R = ((u64)(unsigned)tail[i] << 27) | ((u64)(unsigned)(etype[i] - 1) << 21) | (u64)(unsigned)i;
    rec[slot] = R;
}

// ---- CSR main pass: one wave per head node, 4 edges per iteration ----
// head proj sequential; denom/deg/sum_head in-register (NO atomics);
// only sumtail[tail < N_ITEMS] is atomic.
__global__ __launch_bounds__(256) void node_pass(const float4* __restrict__ proj4,
                                                 const float4* __restrict__ rel4,
                                                 const u64* __restrict__ rec,
                                                 const unsigned* __restrict__ start,
                                                 const unsigned* __restrict__ degi,
                                                 float* __restrict__ logits,
                                                 float2* __restrict__ nd,
                                                 float* __restrict__ sumhead,
                                                 float* __restrict__ sumtail) {
    int wave = (blockIdx.x * blockDim.x + threadIdx.x) >> 6;   // = node id (grid exact)
    int lane = threadIdx.x & 63;
    int slot = lane >> 4, sl = lane & 15;
    unsigned s = start[wave], len = degi[wave];
    float4 ph = proj4[(size_t)wave * 16 + sl];
    float dsum = 0.f, lsum = 0.f;
    for (unsigned k0 = 0; k0 < len; k0 += 4) {
        unsigned k = k0 + slot;
        bool valid = (k < len);
        u64 R = rec[s + (valid ? k : 0u)];
        unsigned t = (unsigned)(R >> 27);
        unsigned r = ((unsigned)(R >> 21)) & 63u;
        unsigned eid = (unsigned)R & 0x1FFFFFu;
        float4 pt = proj4[(size_t)t * 16 + sl];
        float4 pr = rel4[(size_t)r * 16 + sl];
        float v = ph.x * pt.x * pr.x + ph.y * pt.y * pr.y + ph.z * pt.z * pr.z + ph.w * pt.w * pr.w;
        v += __shfl_xor(v, 1, 64);
        v += __shfl_xor(v, 2, 64);
        v += __shfl_xor(v, 4, 64);
        v += __shfl_xor(v, 8, 64);
        if (sl == 0 && valid) {
            float lg = v * SCALE;
            logits[eid] = lg;
            dsum += __expf(lg);
            lsum += lg;
            if (t < N_ITEMS) atomicAdd(&sumtail[t], lg);
        }
    }
    dsum += __shfl_xor(dsum, 16, 64);
    dsum += __shfl_xor(dsum, 32, 64);
    lsum += __shfl_xor(lsum, 16, 64);
    lsum += __shfl_xor(lsum, 32, 64);
    if (lane == 0) {
        nd[wave] = make_float2(dsum, (float)len);
        sumhead[wave] = lsum;
    }
}

// ---- FALLBACK (ws too small): R4 flat edge pass, device-scope atomics ----
__global__ __launch_bounds__(256) void edge_fused_flat(const float4* __restrict__ proj4,
                                                       const float4* __restrict__ rel4,
                                                       const int* __restrict__ head,
                                                       const int* __restrict__ tail,
                                                       const int* __restrict__ etype,
                                                       float* __restrict__ logits,
                                                       float* __restrict__ nd,
                                                       float* __restrict__ sumnode) {
    int wave = (blockIdx.x * blockDim.x + threadIdx.x) >> 6;
    int lane = threadIdx.x & 63;
    int slot = lane >> 4, sl = lane & 15;
    int base = wave * 8;
    int e0 = base + slot, e1 = base + slot + 4;

    int h0 = head[e0], t0 = tail[e0], r0 = etype[e0] - 1;
    int h1 = head[e1], t1 = tail[e1], r1 = etype[e1] - 1;
    float4 a0 = proj4[(size_t)h0 * 16 + sl];
    float4 b0 = proj4[(size_t)t0 * 16 + sl];
    float4 a1 = proj4[(size_t)h1 * 16 + sl];
    float4 b1 = proj4[(size_t)t1 * 16 + sl];
    float4 c0 = rel4[(size_t)r0 * 16 + sl];
    float4 c1 = rel4[(size_t)r1 * 16 + sl];

    float s0 = a0.x * b0.x * c0.x + a0.y * b0.y * c0.y + a0.z * b0.z * c0.z + a0.w * b0.w * c0.w;
    float s1 = a1.x * b1.x * c1.x + a1.y * b1.y * c1.y + a1.z * b1.z * c1.z + a1.w * b1.w * c1.w;
    s0 += __shfl_xor(s0, 1, 64);  s1 += __shfl_xor(s1, 1, 64);
    s0 += __shfl_xor(s0, 2, 64);  s1 += __shfl_xor(s1, 2, 64);
    s0 += __shfl_xor(s0, 4, 64);  s1 += __shfl_xor(s1, 4, 64);
    s0 += __shfl_xor(s0, 8, 64);  s1 += __shfl_xor(s1, 8, 64);

    if (sl == 0) {
        float lg0 = s0 * SCALE, lg1 = s1 * SCALE;
        logits[e0] = lg0;
        logits[e1] = lg1;
        atomicAdd(&nd[2 * h0], __expf(lg0));
        atomicAdd(&nd[2 * h0 + 1], 1.0f);
        atomicAdd(&sumnode[h0], lg0);
        atomicAdd(&sumnode[t0], lg0);
        atomicAdd(&nd[2 * h1], __expf(lg1));
        atomicAdd(&nd[2 * h1 + 1], 1.0f);
        atomicAdd(&sumnode[h1], lg1);
        atomicAdd(&sumnode[t1], lg1);
    }
}

// ---- item keys (a[i] + optional b[i]) + item stage-0 histogram ----
__global__ void reduce_items(const float* __restrict__ a, const float* __restrict__ b,
                             unsigned* __restrict__ keysI, unsigned* __restrict__ histA_I) {
    __shared__ unsigned h[256];
    for (int j = threadIdx.x; j < 256; j += blockDim.x) h[j] = 0;
    __syncthreads();
    int i = blockIdx.x * blockDim.x + threadIdx.x;
    int lane = threadIdx.x & 63;
    unsigned bin = 0;
    bool valid = (i < N_ITEMS);
    if (valid) {
        float s = a[i] + (b ? b[i] : 0.f);
        unsigned k = fkey(s);
        keysI[i] = k;
        bin = k >> 24;
    }
    lds_hist_add(h, bin, valid, lane);
    __syncthreads();
    for (int j = threadIdx.x; j < 256; j += blockDim.x) {
        unsigned v = h[j];
        if (v) atomicAdd(&histA_I[j], v);
    }
}

// ---- scores + gumbel keys + edge stage-0 histogram ----
__global__ void edge_pass3(const float* __restrict__ logits, const int* __restrict__ head,
                           const float2* __restrict__ nd, const float* __restrict__ noise_u,
                           float* __restrict__ out_scores, unsigned* __restrict__ keysE,
                           unsigned* __restrict__ histA_E) {
    __shared__ unsigned h[256];
    for (int j = threadIdx.x; j < 256; j += blockDim.x) h[j] = 0;
    __syncthreads();
    int i = blockIdx.x * blockDim.x + threadIdx.x;
    int lane = threadIdx.x & 63;
    unsigned bin = 0;
    bool valid = (i < N_EDGES);
    if (valid) {
        float lg = logits[i];
        float2 dd = nd[head[i]];
        float score = __expf(lg) / dd.x * dd.y;
        out_scores[i] = score;
        float noise = -logf(-logf(noise_u[i]));
        unsigned k = fkey(score + noise);
        keysE[i] = k;
        bin = k >> 24;
    }
    lds_hist_add(h, bin, valid, lane);
    __syncthreads();
    for (int j = threadIdx.x; j < 256; j += blockDim.x) {
        unsigned v = h[j];
        if (v) atomicAdd(&histA_E[j], v);
    }
}

// ---- radix stages 1,2 (grid.y: 0=edges, 1=items); hists [y][stage][256] ----
__global__ void hist_stage_kernel(const unsigned* __restrict__ keysE,
                                  const unsigned* __restrict__ keysI,
                                  unsigned* __restrict__ hists, int stage) {
    __shared__ unsigned h[256];
    for (int j = threadIdx.x; j < 256; j += blockDim.x) h[j] = 0;
    __syncthreads();
    const int y = blockIdx.y;
    const unsigned* keys = y ? keysI : keysE;
    const int n = y ? N_ITEMS : N_EDGES;
    const unsigned K = y ? K_ITEMS : K_EDGES;
    unsigned* H = hists + (size_t)y * 3 * 256;

    unsigned aboveA, prefix;
    unsigned binA = select_digit(H, K, &aboveA);
    if (stage == 1) {
        prefix = binA;
    } else {
        unsigned aboveB;
        unsigned binB = select_digit(H + 256, K - aboveA, &aboveB);
        prefix = (binA << 8) | binB;
    }
    const int shift = 24 - 8 * stage;
    unsigned* out = H + stage * 256;

    const int lane = threadIdx.x & 63;
    const int stride = gridDim.x * blockDim.x;
    for (int idx = blockIdx.x * blockDim.x + threadIdx.x; idx - lane < n; idx += stride) {
        bool valid = (idx < n);
        unsigned bin = 0;
        if (valid) {
            unsigned k = keys[idx];
            if ((k >> (shift + 8)) != prefix) valid = false;
            bin = (k >> shift) & 0xFFu;
        }
        lds_hist_add(h, bin, valid, lane);
    }
    __syncthreads();
    for (int j = threadIdx.x; j < 256; j += blockDim.x) {
        unsigned v = h[j];
        if (v) atomicAdd(&out[j], v);
    }
}

// ---- collect candidates >= 24-bit threshold ----
__global__ void collect_kernel(const unsigned* __restrict__ keysE,
                               const unsigned* __restrict__ keysI,
                               const unsigned* __restrict__ hists,
                               unsigned* __restrict__ counters, unsigned* __restrict__ cand) {
    const int y = blockIdx.y;
    const unsigned* keys = y ? keysI : keysE;
    const int n = y ? N_ITEMS : N_EDGES;
    const unsigned K = y ? K_ITEMS : K_EDGES;
    const unsigned* H = hists + (size_t)y * 3 * 256;
    unsigned aboveA, aboveB, aboveC;
    unsigned binA = select_digit(H, K, &aboveA);
    unsigned binB = select_digit(H + 256, K - aboveA, &aboveB);
    unsigned binC = select_digit(H + 512, K - aboveA - aboveB, &aboveC);
    const unsigned T = ((binA << 16) | (binB << 8) | binC) << 8;
    unsigned* cd = cand + (size_t)y * 2 * CAND_CAP;

    int i = blockIdx.x * blockDim.x + threadIdx.x;
    int stride = gridDim.x * blockDim.x;
    for (; i < n; i += stride) {
        unsigned k = keys[i];
        if (k >= T) {
            unsigned p = atomicAdd(&counters[y], 1u);
            if (p < (unsigned)CAND_CAP) { cd[2 * p] = k; cd[2 * p + 1] = (unsigned)i; }
        }
    }
}

// ---- exact rank among candidates (key desc, index asc); 2 blocks (y) ----
__global__ void final_topk_kernel(const unsigned* __restrict__ cand,
                                  const unsigned* __restrict__ counters,
                                  float* __restrict__ out_topkv, float* __restrict__ out_topki,
                                  float* __restrict__ out_itemv, float* __restrict__ out_itemi) {
    __shared__ unsigned sk[CAND_CAP];
    __shared__ unsigned si[CAND_CAP];
    const int y = blockIdx.x;
    const int K = y ? K_ITEMS : K_EDGES;
    float* outv = y ? out_itemv : out_topkv;
    float* outi = y ? out_itemi : out_topki;
    const unsigned* cd = cand + (size_t)y * 2 * CAND_CAP;
    unsigned m = counters[y];
    if (m > (unsigned)CAND_CAP) m = CAND_CAP;
    for (unsigned i = threadIdx.x; i < m; i += blockDim.x) {
        sk[i] = cd[2 * i];
        si[i] = cd[2 * i + 1];
    }
    __syncthreads();
    for (unsigned i = threadIdx.x; i < m; i += blockDim.x) {
        unsigned ki = sk[i], xi = si[i];
        int r = 0;
        for (unsigned j = 0; j < m; ++j) {
            unsigned kj = sk[j];
            if (kj > ki || (kj == ki && si[j] < xi)) r++;
        }
        if (r < K) {
            outv[r] = funkey(ki);
            outi[r] = (float)xi;
        }
    }
}

extern "C" void kernel_launch(void* const* d_in, const int* in_sizes, int n_in,
                              void* d_out, int out_size, void* d_ws, size_t ws_size,
                              hipStream_t stream) {
    (void)in_sizes; (void)n_in; (void)out_size;
    const float* emb    = (const float*)d_in[0];
    const float* W      = (const float*)d_in[1];
    const float* rel    = (const float*)d_in[2];
    const float* noise  = (const float*)d_in[3];
    const int*   eidx   = (const int*)d_in[4];
    const int*   etype  = (const int*)d_in[5];
    const int* head = eidx;
    const int* tail = eidx + N_EDGES;

    float* out        = (float*)d_out;
    float* out_scores = out;
    float* out_topkv  = out + N_EDGES;
    float* out_topki  = out + N_EDGES + K_EDGES;
    float* out_itemv  = out + N_EDGES + 2 * K_EDGES;
    float* out_itemi  = out + N_EDGES + 2 * K_EDGES + K_ITEMS;

    // CSR layout size (floats): proj + logits + rec(2E) + start + degi +
    // sumtail + hists + counters + nd + sumhead + bsum + bscan + cand
    const size_t CSR_FLOATS = (size_t)N_ENTITIES * DIM + N_EDGES + 2 * (size_t)N_EDGES
                            + N_ENTITIES + N_ENTITIES + N_ITEMS + 2 * 3 * 256 + 2
                            + 2 * (size_t)N_ENTITIES + N_ENTITIES + 1024 + 1024
                            + 2 * 2 * CAND_CAP;
    const bool csr = ws_size >= CSR_FLOATS * 4;

    float* ws = (float*)d_ws;

    if (csr) {
        size_t o = 0;
        float*    proj    = ws + o;               o += (size_t)N_ENTITIES * DIM;
        float*    logits  = ws + o;                                       // pos aliases here
        unsigned* pos     = (unsigned*)logits;    o += N_EDGES;           // (pos dead before logits written)
        u64*      rec     = (u64*)(ws + o);       o += 2 * (size_t)N_EDGES;
        unsigned* keysE   = (unsigned*)rec;                               // written in pass3, rec dead by then
        unsigned* keysI   = keysE + N_EDGES;
        unsigned* start   = (unsigned*)(ws + o);  o += N_ENTITIES;
        unsigned* degi    = (unsigned*)(ws + o);  o += N_ENTITIES;        // memset block begins
        float*    sumtail = ws + o;               o += N_ITEMS;
        unsigned* hists   = (unsigned*)(ws + o);  o += 2 * 3 * 256;
        unsigned* counters= (unsigned*)(ws + o);  o += 2;                 // memset block ends
        float2*   nd      = (float2*)(ws + o);    o += 2 * (size_t)N_ENTITIES;
        float*    sumhead = ws + o;               o += N_ENTITIES;
        unsigned* bsum    = (unsigned*)(ws + o);  o += 1024;
        unsigned* bscan   = (unsigned*)(ws + o);  o += 1024;
        unsigned* cand    = (unsigned*)(ws + o);  o += 2 * 2 * CAND_CAP;

        // zero: degi + sumtail + hists + counters (contiguous)
        hipMemsetAsync(degi, 0, (size_t)(N_ENTITIES + N_ITEMS + 2 * 3 * 256 + 2) * 4, stream);
        // proj + fused head histogram
        hipLaunchKernelGGL(proj_kernel, dim3(12500), dim3(256), 0, stream,
                           emb, W, proj, head, degi);
        // exclusive scan -> start, pos
        hipLaunchKernelGGL(scan1_kernel, dim3(NSCANB), dim3(256), 0, stream, degi, start, bsum);
        hipLaunchKernelGGL(scan2_kernel, dim3(1), dim3(1024), 0, stream, bsum, bscan);
        hipLaunchKernelGGL(scan3_kernel, dim3(NSCANB), dim3(256), 0, stream, start, bscan, pos);
        // scatter into CSR
        hipLaunchKernelGGL(scatter_kernel, dim3((N_EDGES + 255) / 256), dim3(256), 0, stream,
                           head, tail, etype, pos, rec);
        // CSR main pass: one wave per node (200000 waves = 50000 blocks)
        hipLaunchKernelGGL(node_pass, dim3(N_ENTITIES / 4), dim3(256), 0, stream,
                           (const float4*)proj, (const float4*)rel, rec, start, degi,
                           logits, nd, sumhead, sumtail);
        // item keys + item stage-0 hist
        hipLaunchKernelGGL(reduce_items, dim3((N_ITEMS + 255) / 256), dim3(256), 0, stream,
                           sumhead, sumtail, keysI, hists + 3 * 256);
        // scores + noisy keys + edge stage-0 hist
        hipLaunchKernelGGL(edge_pass3, dim3((N_EDGES + 255) / 256), dim3(256), 0, stream,
                           logits, head, (const float2*)nd, noise, out_scores, keysE, hists);
        // shared top-k pipeline
        hipLaunchKernelGGL(hist_stage_kernel, dim3(512, 2), dim3(256), 0, stream,
                           keysE, keysI, hists, 1);
        hipLaunchKernelGGL(hist_stage_kernel, dim3(512, 2), dim3(256), 0, stream,
                           keysE, keysI, hists, 2);
        hipLaunchKernelGGL(collect_kernel, dim3(512, 2), dim3(256), 0, stream,
                           keysE, keysI, hists, counters, cand);
        hipLaunchKernelGGL(final_topk_kernel, dim3(2), dim3(1024), 0, stream,
                           cand, counters, out_topkv, out_topki, out_itemv, out_itemi);
    } else {
        // ---- fallback: proven R4 flat path ----
        size_t o = 0;
        float*    proj    = ws + o;               o += (size_t)N_ENTITIES * DIM;
        float*    logits  = ws + o;               o += N_EDGES;
        unsigned* keysE   = (unsigned*)(ws + o);  o += N_EDGES;
        unsigned* keysI   = (unsigned*)(ws + o);  o += N_ITEMS;
        float*    nd      = ws + o;               o += 2 * (size_t)N_ENTITIES; // memset begins
        float*    sumnode = ws + o;               o += N_ENTITIES;
        unsigned* hists   = (unsigned*)(ws + o);  o += 2 * 3 * 256;
        unsigned* counters= (unsigned*)(ws + o);  o += 2;                      // memset ends
        unsigned* cand    = (unsigned*)(ws + o);  o += 2 * 2 * CAND_CAP;

        hipMemsetAsync(nd, 0, (size_t)(3 * N_ENTITIES + 2 * 3 * 256 + 2) * 4, stream);
        hipLaunchKernelGGL(proj_kernel, dim3(12500), dim3(256), 0, stream,
                           emb, W, proj, (const int*)nullptr, (unsigned*)nullptr);
        hipLaunchKernelGGL(edge_fused_flat, dim3(N_EDGES / 8 / 4), dim3(256), 0, stream,
                           (const float4*)proj, (const float4*)rel, head, tail, etype,
                           logits, nd, sumnode);
        hipLaunchKernelGGL(reduce_items, dim3((N_ITEMS + 255) / 256), dim3(256), 0, stream,
                           sumnode, (const float*)nullptr, keysI, hists + 3 * 256);
        hipLaunchKernelGGL(edge_pass3, dim3((N_EDGES + 255) / 256), dim3(256), 0, stream,
                           logits, head, (const float2*)nd, noise, out_scores, keysE, hists);
        hipLaunchKernelGGL(hist_stage_kernel, dim3(512, 2), dim3(256), 0, stream,
                           keysE, keysI, hists, 1);
        hipLaunchKernelGGL(hist_stage_kernel, dim3(512, 2), dim3(256), 0, stream,
                           keysE, keysI, hists, 2);
        hipLaunchKernelGGL(collect_kernel, dim3(512, 2), dim3(256), 0, stream,
                           keysE, keysI, hists, counters, cand);
        hipLaunchKernelGGL(final_topk_kernel, dim3(2), dim3(1024), 0, stream,
                           cand, counters, out_topkv, out_topki, out_itemv, out_itemi);
    }
}